// Round 1
// baseline (127.580 us; speedup 1.0000x reference)
//
#include <hip/hip_runtime.h>
#include <hip/hip_bf16.h>

// HybridLoss: focal(preds,targets) + contrastive(features,targets) + 0.1*graph_reg(graph_features)
// N=8192, D=128. Contrastive = mean over N^2 pairs of
//   same ? sq : max(1 - sqrt(sq), 0)^2,  sq = ||fi||^2 + ||fj||^2 - 2 fi.fj
// Strategy: bf16 MFMA Gram matrix, upper-triangular blocks x2 weight, fused epilogue reduce.

#define N_PTS 8192
#define DIM 128

typedef __bf16 bf16x8 __attribute__((ext_vector_type(8)));
typedef float f32x4 __attribute__((ext_vector_type(4)));

// workspace layout (bytes)
#define FBF_OFF   0                          // __bf16[8192*128] = 2 MB
#define SQN_OFF   (N_PTS * DIM * 2)          // float[8192] = 32 KB
#define CPART_OFF (SQN_OFF + N_PTS * 4)      // float[4096]
#define FPART_OFF (CPART_OFF + 4096 * 4)     // float[32]
#define GPART_OFF (FPART_OFF + 32 * 4)       // float[256]

// ---------------- prep: fp32 -> bf16 copy of features + row squared norms (fp32) ----
__global__ __launch_bounds__(256) void prep_kernel(const float* __restrict__ feat,
                                                   __bf16* __restrict__ fbf,
                                                   float* __restrict__ sqn) {
    const int w = threadIdx.x >> 6;
    const int lane = threadIdx.x & 63;
    const int r = blockIdx.x * 4 + w;          // one wave per row, 2048 blocks
    const float2 v = *reinterpret_cast<const float2*>(feat + r * DIM + lane * 2);
    union { __bf16 h[2]; unsigned u; } pk;
    pk.h[0] = (__bf16)v.x; pk.h[1] = (__bf16)v.y;
    reinterpret_cast<unsigned*>(fbf)[r * (DIM / 2) + lane] = pk.u;
    float s = v.x * v.x + v.y * v.y;
    #pragma unroll
    for (int off = 32; off > 0; off >>= 1) s += __shfl_down(s, off);
    if (lane == 0) sqn[r] = s;
}

// ---------------- focal loss partials ----------------
__global__ __launch_bounds__(256) void focal_kernel(const float* __restrict__ preds,
                                                    const float* __restrict__ targets,
                                                    float* __restrict__ f_part) {
    const int i = blockIdx.x * 256 + threadIdx.x;
    const float p = preds[i], t = targets[i];
    const float bce = fmaxf(p, 0.f) - p * t + log1pf(expf(-fabsf(p)));
    const float pt = expf(-bce);
    const float om = 1.f - pt;
    float v = 0.25f * om * om * bce;
    #pragma unroll
    for (int off = 32; off > 0; off >>= 1) v += __shfl_down(v, off);
    __shared__ float red[4];
    if ((threadIdx.x & 63) == 0) red[threadIdx.x >> 6] = v;
    __syncthreads();
    if (threadIdx.x == 0) f_part[blockIdx.x] = red[0] + red[1] + red[2] + red[3];
}

// ---------------- graph regularizer partials ----------------
__global__ __launch_bounds__(256) void graph_kernel(const float* __restrict__ gf,
                                                    float* __restrict__ g_part) {
    const int w = threadIdx.x >> 6;
    const int lane = threadIdx.x & 63;
    float acc = 0.f;
    #pragma unroll
    for (int it = 0; it < 8; ++it) {
        const int r = blockIdx.x * 4 + w + it * 1024;   // wave-uniform
        if (r < N_PTS - 1) {
            const float2 a = *reinterpret_cast<const float2*>(gf + r * DIM + lane * 2);
            const float2 b = *reinterpret_cast<const float2*>(gf + (r + 1) * DIM + lane * 2);
            const float dx = b.x - a.x, dy = b.y - a.y;
            float s = dx * dx + dy * dy;
            #pragma unroll
            for (int off = 32; off > 0; off >>= 1) s += __shfl_down(s, off);
            if (lane == 0) acc += sqrtf(s);
        }
    }
    __shared__ float red[4];
    if (lane == 0) red[w] = acc;
    __syncthreads();
    if (threadIdx.x == 0) g_part[blockIdx.x] = red[0] + red[1] + red[2] + red[3];
}

// ---------------- main: 128x128 Gram tiles via MFMA + fused contrastive epilogue ----
// LDS: A tile [0,32K), B tile [32K,64K). 16B chunks, XOR-swizzled: row r chunk c
// stored at slot (c ^ (r&15)) within the row -> conflict-free ds_read_b128.
__global__ __launch_bounds__(256) void pair_kernel(const __bf16* __restrict__ fbf,
                                                   const float* __restrict__ sqn,
                                                   const float* __restrict__ targets,
                                                   float* __restrict__ c_part) {
    const int bi = blockIdx.x, bj = blockIdx.y;
    const int bid = bj * 64 + bi;
    if (bj < bi) {                       // lower triangle: symmetric, skip
        if (threadIdx.x == 0) c_part[bid] = 0.f;
        return;
    }
    __shared__ __align__(16) char smem[65536];
    const int tid = threadIdx.x;
    const int lane = tid & 63;
    const int wv = tid >> 6;
    const int quad = lane >> 4;
    const int m15 = lane & 15;
    const int ibase = bi * 128, jbase = bj * 128;

    // stage A+B tiles (swizzled). p in [0,4096) chunk positions of 16B.
    #pragma unroll
    for (int it = 0; it < 16; ++it) {
        const int p = it * 256 + tid;
        const int r = (p & 2047) >> 4;       // row within tile
        const int s = p & 15;                // stored slot
        const int c = s ^ (r & 15);          // source chunk
        const int grow = ((p >> 11) ? jbase : ibase) + r;
        const uint4 v = *reinterpret_cast<const uint4*>(
            reinterpret_cast<const char*>(fbf) + grow * 256 + c * 16);
        *reinterpret_cast<uint4*>(smem + p * 16) = v;
    }
    __syncthreads();

    const int wm = wv >> 1, wn = wv & 1;     // wave computes 64x64 sub-tile
    f32x4 acc[4][4];
    #pragma unroll
    for (int a = 0; a < 4; ++a)
        #pragma unroll
        for (int b = 0; b < 4; ++b) acc[a][b] = (f32x4){0.f, 0.f, 0.f, 0.f};

    #pragma unroll
    for (int ks = 0; ks < 4; ++ks) {
        const int c = ks * 4 + quad;
        const int sw = (c ^ m15) << 4;       // swizzled byte offset within row
        bf16x8 af[4], bfv[4];
        #pragma unroll
        for (int t = 0; t < 4; ++t) {
            const int ra = wm * 64 + t * 16 + m15;
            const int rb = wn * 64 + t * 16 + m15;
            af[t]  = *reinterpret_cast<const bf16x8*>(smem + ra * 256 + sw);
            bfv[t] = *reinterpret_cast<const bf16x8*>(smem + 32768 + rb * 256 + sw);
        }
        #pragma unroll
        for (int tm = 0; tm < 4; ++tm)
            #pragma unroll
            for (int tn = 0; tn < 4; ++tn)
                acc[tm][tn] = __builtin_amdgcn_mfma_f32_16x16x32_bf16(
                    af[tm], bfv[tn], acc[tm][tn], 0, 0, 0);
    }

    // epilogue: sq = sqn_i + sqn_j - 2g ; same ? sq : relu(1-sqrt(sq))^2
    const bool diag = (bi == bj);
    float lsum = 0.f;
    #pragma unroll
    for (int tm = 0; tm < 4; ++tm) {
        const int i0 = wm * 64 + tm * 16 + quad * 4;   // local row of reg 0
        const f32x4 sqni = *reinterpret_cast<const f32x4*>(sqn + ibase + i0);
        const f32x4 ti   = *reinterpret_cast<const f32x4*>(targets + ibase + i0);
        #pragma unroll
        for (int tn = 0; tn < 4; ++tn) {
            const int jl = wn * 64 + tn * 16 + m15;
            const float sqnj = sqn[jbase + jl];
            const float tj = targets[jbase + jl];
            #pragma unroll
            for (int e = 0; e < 4; ++e) {
                const float g = acc[tm][tn][e];
                const float sq = fmaxf(sqni[e] + sqnj - 2.f * g, 0.f);
                const float d = sqrtf(sq);
                const float m = fmaxf(1.f - d, 0.f);
                const float v = (ti[e] == tj) ? sq : m * m;
                float w;
                if (!diag) {
                    w = 2.f;
                } else {
                    const int il = i0 + e;
                    w = (jl > il) ? 2.f : ((jl == il) ? 1.f : 0.f);
                }
                lsum += w * v;
            }
        }
    }
    #pragma unroll
    for (int off = 32; off > 0; off >>= 1) lsum += __shfl_down(lsum, off);
    __syncthreads();                          // tiles no longer needed; reuse smem
    float* red = reinterpret_cast<float*>(smem);
    if (lane == 0) red[wv] = lsum;
    __syncthreads();
    if (tid == 0) c_part[bid] = red[0] + red[1] + red[2] + red[3];
}

// ---------------- finalize ----------------
__global__ __launch_bounds__(256) void finalize_kernel(const float* __restrict__ c_part,
                                                       const float* __restrict__ f_part,
                                                       const float* __restrict__ g_part,
                                                       float* __restrict__ out) {
    const int tid = threadIdx.x;
    float c = 0.f;
    for (int i = tid; i < 4096; i += 256) c += c_part[i];
    float f = (tid < 32) ? f_part[tid] : 0.f;
    float g = g_part[tid];
    #pragma unroll
    for (int off = 32; off > 0; off >>= 1) {
        c += __shfl_down(c, off);
        f += __shfl_down(f, off);
        g += __shfl_down(g, off);
    }
    __shared__ float red[12];
    const int w = tid >> 6, lane = tid & 63;
    if (lane == 0) { red[w] = c; red[4 + w] = f; red[8 + w] = g; }
    __syncthreads();
    if (tid == 0) {
        const float cs = red[0] + red[1] + red[2] + red[3];
        const float fs = red[4] + red[5] + red[6] + red[7];
        const float gs = red[8] + red[9] + red[10] + red[11];
        out[0] = cs / (8192.f * 8192.f) + fs / 8192.f + 0.1f * (gs / 8191.f);
    }
}

extern "C" void kernel_launch(void* const* d_in, const int* in_sizes, int n_in,
                              void* d_out, int out_size, void* d_ws, size_t ws_size,
                              hipStream_t stream) {
    const float* preds    = (const float*)d_in[0];
    const float* targets  = (const float*)d_in[1];
    const float* features = (const float*)d_in[2];
    const float* gfeat    = (const float*)d_in[3];
    char* ws = (char*)d_ws;
    __bf16* fbf   = (__bf16*)(ws + FBF_OFF);
    float* sqn    = (float*)(ws + SQN_OFF);
    float* c_part = (float*)(ws + CPART_OFF);
    float* f_part = (float*)(ws + FPART_OFF);
    float* g_part = (float*)(ws + GPART_OFF);
    float* out = (float*)d_out;

    prep_kernel<<<2048, 256, 0, stream>>>(features, fbf, sqn);
    focal_kernel<<<32, 256, 0, stream>>>(preds, targets, f_part);
    graph_kernel<<<256, 256, 0, stream>>>(gfeat, g_part);
    pair_kernel<<<dim3(64, 64), 256, 0, stream>>>(fbf, sqn, targets, c_part);
    finalize_kernel<<<1, 256, 0, stream>>>(c_part, f_part, g_part, out);
}